// Round 2
// baseline (285.329 us; speedup 1.0000x reference)
//
#include <hip/hip_runtime.h>
#include <math.h>

#define IMG 256
#define PIX (IMG * IMG)

// ---------------------------------------------------------------------------
// Mesh renderer forward pass, exact f32 replication of the JAX reference.
// All discrete-decision math (edge functions, barycentrics, z-test) is done
// with contraction OFF and in the reference's association order so that
// inside/valid/z-winner decisions match the numpy reference bit-for-bit.
// ---------------------------------------------------------------------------

// K1: transform + project all vertices; also zero the vertex-normal buffer.
__global__ __launch_bounds__(256) void k_transform(
    const float* __restrict__ verts, const float* __restrict__ tm,
    const float* __restrict__ focal, const float* __restrict__ pp,
    float* __restrict__ vp, float* __restrict__ vn, int B, int V) {
#pragma clang fp contract(off)
    int idx = blockIdx.x * blockDim.x + threadIdx.x;
    if (idx >= B * V) return;
    int b = idx / V;
    const float* tmb = tm + b * 16;
    float x = verts[idx * 3 + 0];
    float y = verts[idx * 3 + 1];
    float z = verts[idx * 3 + 2];
    float vv[3];
    for (int j = 0; j < 3; ++j) {
        // einsum('bvi,bij->bvj'): sum_i v_i * R[i][j], then + T[j]
        float s = x * tmb[0 * 4 + j] + y * tmb[1 * 4 + j];
        s = s + z * tmb[2 * 4 + j];
        vv[j] = s + tmb[j * 4 + 3];
    }
    float f = focal[b];
    float xp = (f * vv[0]) / vv[2] + pp[0];
    float yp = (f * vv[1]) / vv[2] + pp[1];
    vp[idx * 3 + 0] = xp;
    vp[idx * 3 + 1] = yp;
    vp[idx * 3 + 2] = vv[2];
    vn[idx * 3 + 0] = 0.0f;
    vn[idx * 3 + 1] = 0.0f;
    vn[idx * 3 + 2] = 0.0f;
}

// K2: pack per-face screen-space triangle (9 floats) + bbox (4 floats);
// also accumulate world-space face normals into vertex normals (atomics).
__global__ __launch_bounds__(256) void k_pack(
    const float* __restrict__ verts, const int* __restrict__ faces,
    const float* __restrict__ vp, float* __restrict__ packed,
    float* __restrict__ bbox, float* __restrict__ vn,
    int B, int F, int FP, int V) {
#pragma clang fp contract(off)
    int idx = blockIdx.x * blockDim.x + threadIdx.x;
    if (idx >= B * FP) return;
    int b = idx / FP;
    int f = idx - b * FP;
    int i0 = 0, i1 = 0, i2 = 0;
    if (f < F) {
        i0 = faces[f * 3 + 0];
        i1 = faces[f * 3 + 1];
        i2 = faces[f * 3 + 2];
    }
    const float* vpb = vp + (size_t)b * V * 3;
    float x0 = vpb[i0 * 3 + 0], y0 = vpb[i0 * 3 + 1], z0 = vpb[i0 * 3 + 2];
    float x1 = vpb[i1 * 3 + 0], y1 = vpb[i1 * 3 + 1], z1 = vpb[i1 * 3 + 2];
    float x2 = vpb[i2 * 3 + 0], y2 = vpb[i2 * 3 + 1], z2 = vpb[i2 * 3 + 2];
    float* pk = packed + (size_t)idx * 9;
    pk[0] = x0; pk[1] = y0; pk[2] = z0;
    pk[3] = x1; pk[4] = y1; pk[5] = z1;
    pk[6] = x2; pk[7] = y2; pk[8] = z2;
    float4 bb;
    bb.x = fminf(fminf(x0, x1), x2);  // xmin
    bb.y = fmaxf(fmaxf(x0, x1), x2);  // xmax
    bb.z = fminf(fminf(y0, y1), y2);  // ymin
    bb.w = fmaxf(fmaxf(y0, y1), y2);  // ymax
    ((float4*)bbox)[idx] = bb;
    if (f < F) {
        const float* wv = verts + (size_t)b * V * 3;
        float ax = wv[i1 * 3 + 0] - wv[i0 * 3 + 0];
        float ay = wv[i1 * 3 + 1] - wv[i0 * 3 + 1];
        float az = wv[i1 * 3 + 2] - wv[i0 * 3 + 2];
        float bx = wv[i2 * 3 + 0] - wv[i0 * 3 + 0];
        float by = wv[i2 * 3 + 1] - wv[i0 * 3 + 1];
        float bz = wv[i2 * 3 + 2] - wv[i0 * 3 + 2];
        float fnx = ay * bz - az * by;
        float fny = az * bx - ax * bz;
        float fnz = ax * by - ay * bx;
        float* vnb = vn + (size_t)b * V * 3;
        atomicAdd(&vnb[i0 * 3 + 0], fnx);
        atomicAdd(&vnb[i0 * 3 + 1], fny);
        atomicAdd(&vnb[i0 * 3 + 2], fnz);
        atomicAdd(&vnb[i1 * 3 + 0], fnx);
        atomicAdd(&vnb[i1 * 3 + 1], fny);
        atomicAdd(&vnb[i1 * 3 + 2], fnz);
        atomicAdd(&vnb[i2 * 3 + 0], fnx);
        atomicAdd(&vnb[i2 * 3 + 1], fny);
        atomicAdd(&vnb[i2 * 3 + 2], fnz);
    }
}

// K3: normalize vertex normals.
__global__ __launch_bounds__(256) void k_normvn(float* __restrict__ vn, int n) {
#pragma clang fp contract(off)
    int idx = blockIdx.x * blockDim.x + threadIdx.x;
    if (idx >= n) return;
    float x = vn[idx * 3 + 0];
    float y = vn[idx * 3 + 1];
    float z = vn[idx * 3 + 2];
    float nrm = sqrtf((x * x + y * y) + z * z) + 1e-8f;
    vn[idx * 3 + 0] = x / nrm;
    vn[idx * 3 + 1] = y / nrm;
    vn[idx * 3 + 2] = z / nrm;
}

// K4: z-buffer rasterization. One block = one 16x16 pixel tile, one thread
// per pixel. Faces are culled per 256-face chunk via bbox + __ballot; the
// survivors are walked IN FACE ORDER (preserves the reference tie-break:
// first face attaining the minimum z wins).
__global__ __launch_bounds__(256) void k_raster(
    const float* __restrict__ packed, const float* __restrict__ bbox,
    float* __restrict__ zbuf, int* __restrict__ fidbuf, int FP) {
#pragma clang fp contract(off)
    int b = blockIdx.y;
    int tid = threadIdx.x;
    int tile = blockIdx.x;                   // 0..255, 16x16 tiles
    int tx0 = (tile & 15) * 16;
    int ty0 = (tile >> 4) * 16;
    float px = (float)(tx0 + (tid & 15)) + 0.5f;
    float py = (float)(ty0 + (tid >> 4)) + 0.5f;
    // tile pixel-center range [tx0+0.5, tx0+15.5], margin 0.5px (conservative;
    // f32 edge-function slop is ~1e-4 px).
    float txlo = (float)tx0, txhi = (float)(tx0 + 16);
    float tylo = (float)ty0, tyhi = (float)(ty0 + 16);

    const float* pb = packed + (size_t)b * FP * 9;
    const float4* bb = (const float4*)bbox + (size_t)b * FP;

    float best = INFINITY;
    int bestf = 0;
    __shared__ unsigned long long masks[4];

    int nchunks = FP / 256;
    for (int c = 0; c < nchunks; ++c) {
        int fidx = c * 256 + tid;
        float4 bx = bb[fidx];
        bool pred = (bx.x <= txhi) && (bx.y >= txlo) &&
                    (bx.z <= tyhi) && (bx.w >= tylo);
        unsigned long long m = __ballot(pred);
        if ((tid & 63) == 0) masks[tid >> 6] = m;
        __syncthreads();
        for (int w = 0; w < 4; ++w) {
            unsigned long long mm = masks[w];
            while (mm) {
                int bit = __ffsll(mm) - 1;
                mm &= (mm - 1);
                int f = c * 256 + w * 64 + bit;
                const float* t = pb + (size_t)f * 9;
                float x0 = t[0], y0 = t[1], z0 = t[2];
                float x1 = t[3], y1 = t[4], z1 = t[5];
                float x2 = t[6], y2 = t[7], z2 = t[8];
                // _edge(a,b,p) = (bx-ax)*(py-ay) - (by-ay)*(px-ax)
                float w0 = (x2 - x1) * (py - y1) - (y2 - y1) * (px - x1);
                float w1 = (x0 - x2) * (py - y2) - (y0 - y2) * (px - x2);
                float w2 = (x1 - x0) * (py - y0) - (y1 - y0) * (px - x0);
                float denom = (w0 + w1) + w2;
                bool dok = fabsf(denom) > 1e-8f;
                float safe = dok ? denom : 1.0f;
                float b0 = w0 / safe;
                float b1 = w1 / safe;
                float b2 = w2 / safe;
                float zint = (b0 * z0 + b1 * z1) + b2 * z2;
                bool inside = (b0 >= 0.0f) && (b1 >= 0.0f) && (b2 >= 0.0f) &&
                              dok && (zint > 1e-4f);
                if (inside && zint < best) {
                    best = zint;
                    bestf = f;
                }
            }
        }
        __syncthreads();
    }
    int p = (ty0 + (tid >> 4)) * IMG + tx0 + (tid & 15);
    zbuf[(size_t)b * PIX + p] = best;
    fidbuf[(size_t)b * PIX + p] = bestf;
}

// K5: shading. Recompute barycentrics for the winning face exactly as the
// reference does, gather world positions / vertex normals, Phong.
__global__ __launch_bounds__(256) void k_shade(
    const float* __restrict__ verts, const int* __restrict__ faces,
    const float* __restrict__ tm, const float* __restrict__ packed,
    const float* __restrict__ vn, const float* __restrict__ zbuf,
    const int* __restrict__ fidbuf, float* __restrict__ out,
    int B, int V, int FP) {
#pragma clang fp contract(off)
    int p = blockIdx.x * blockDim.x + threadIdx.x;
    int b = blockIdx.y;
    if (p >= PIX) return;
    size_t imgbase = (size_t)b * 3 * PIX;
    size_t alphabase = (size_t)B * 3 * PIX + (size_t)b * PIX;
    float z = zbuf[(size_t)b * PIX + p];
    if (!isfinite(z)) {
        out[imgbase + 0 * PIX + p] = 255.0f;
        out[imgbase + 1 * PIX + p] = 255.0f;
        out[imgbase + 2 * PIX + p] = 255.0f;
        out[alphabase + p] = 0.0f;
        return;
    }
    int f = fidbuf[(size_t)b * PIX + p];
    float px = (float)(p & (IMG - 1)) + 0.5f;
    float py = (float)(p >> 8) + 0.5f;
    const float* t = packed + ((size_t)b * FP + f) * 9;
    float x0 = t[0], y0 = t[1];
    float x1 = t[3], y1 = t[4];
    float x2 = t[6], y2 = t[7];
    float w0 = (x2 - x1) * (py - y1) - (y2 - y1) * (px - x1);
    float w1 = (x0 - x2) * (py - y2) - (y0 - y2) * (px - x2);
    float w2 = (x1 - x0) * (py - y0) - (y1 - y0) * (px - x0);
    float denom = (w0 + w1) + w2;
    float safe = (fabsf(denom) > 1e-8f) ? denom : 1.0f;
    float b0 = w0 / safe;
    float b1 = w1 / safe;
    float b2 = w2 / safe;

    int i0 = faces[f * 3 + 0];
    int i1 = faces[f * 3 + 1];
    int i2 = faces[f * 3 + 2];
    const float* wv = verts + (size_t)b * V * 3;
    const float* vnb = vn + (size_t)b * V * 3;

    float pos[3], nr[3];
    for (int c = 0; c < 3; ++c) {
        pos[c] = (b0 * wv[i0 * 3 + c] + b1 * wv[i1 * 3 + c]) + b2 * wv[i2 * 3 + c];
        nr[c]  = (b0 * vnb[i0 * 3 + c] + b1 * vnb[i1 * 3 + c]) + b2 * vnb[i2 * 3 + c];
    }
    float nl = sqrtf((nr[0] * nr[0] + nr[1] * nr[1]) + nr[2] * nr[2]) + 1e-8f;
    nr[0] = nr[0] / nl; nr[1] = nr[1] / nl; nr[2] = nr[2] / nl;

    // cam_i = -sum_j T_j * R[i][j]
    const float* tmb = tm + b * 16;
    float T0 = tmb[3], T1 = tmb[7], T2 = tmb[11];
    float cam[3];
    for (int i = 0; i < 3; ++i)
        cam[i] = -((T0 * tmb[i * 4 + 0] + T1 * tmb[i * 4 + 1]) + T2 * tmb[i * 4 + 2]);

    // L = normalize(light - pos), light = (0,0,3)
    float Lx = 0.0f - pos[0], Ly = 0.0f - pos[1], Lz = 3.0f - pos[2];
    float Ln = sqrtf((Lx * Lx + Ly * Ly) + Lz * Lz) + 1e-8f;
    Lx = Lx / Ln; Ly = Ly / Ln; Lz = Lz / Ln;
    // Vd = normalize(cam - pos)
    float Vx = cam[0] - pos[0], Vy = cam[1] - pos[1], Vz = cam[2] - pos[2];
    float Vn2 = sqrtf((Vx * Vx + Vy * Vy) + Vz * Vz) + 1e-8f;
    Vx = Vx / Vn2; Vy = Vy / Vn2; Vz = Vz / Vn2;

    float ndl = (nr[0] * Lx + nr[1] * Ly) + nr[2] * Lz;
    float t2 = 2.0f * ndl;
    float rx = (t2 * nr[0]) - Lx;
    float ry = (t2 * nr[1]) - Ly;
    float rz = (t2 * nr[2]) - Lz;
    float rv = (rx * Vx + ry * Vy) + rz * Vz;
    float sp = powf(fmaxf(rv, 0.0f), 64.0f);
    float spec = (0.2f * sp) * ((ndl > 0.0f) ? 1.0f : 0.0f);
    float col = (0.5f + 0.3f * fmaxf(ndl, 0.0f)) + spec;
    col = col * 255.0f;
    out[imgbase + 0 * PIX + p] = col;
    out[imgbase + 1 * PIX + p] = col;
    out[imgbase + 2 * PIX + p] = col;
    out[alphabase + p] = 1.0f;
}

extern "C" void kernel_launch(void* const* d_in, const int* in_sizes, int n_in,
                              void* d_out, int out_size, void* d_ws, size_t ws_size,
                              hipStream_t stream) {
    const float* verts = (const float*)d_in[0];
    const float* tm    = (const float*)d_in[1];
    const float* focal = (const float*)d_in[2];
    const float* pp    = (const float*)d_in[3];
    const int*   faces = (const int*)d_in[4];

    int B = in_sizes[1] / 16;
    int V = in_sizes[0] / (3 * B);
    int F = in_sizes[4] / 3;
    int FP = ((F + 255) / 256) * 256;  // pad to chunk multiple; pads are inert

    float* out = (float*)d_out;

    // workspace layout (floats)
    float* vp     = (float*)d_ws;            // B*V*3
    float* vn     = vp + (size_t)B * V * 3;  // B*V*3
    float* packed = vn + (size_t)B * V * 3;  // B*FP*9
    float* bbox   = packed + (size_t)B * FP * 9;  // B*FP*4 (16B aligned)
    float* zbuf   = bbox + (size_t)B * FP * 4;    // B*PIX
    int*   fid    = (int*)(zbuf + (size_t)B * PIX);  // B*PIX

    int nv = B * V;
    k_transform<<<dim3((nv + 255) / 256), dim3(256), 0, stream>>>(
        verts, tm, focal, pp, vp, vn, B, V);
    k_pack<<<dim3((B * FP + 255) / 256), dim3(256), 0, stream>>>(
        verts, faces, vp, packed, bbox, vn, B, F, FP, V);
    k_normvn<<<dim3((nv + 255) / 256), dim3(256), 0, stream>>>(vn, nv);
    k_raster<<<dim3(256, B), dim3(256), 0, stream>>>(packed, bbox, zbuf, fid, FP);
    k_shade<<<dim3(PIX / 256, B), dim3(256), 0, stream>>>(
        verts, faces, tm, packed, vn, zbuf, fid, out, B, V, FP);
}

// Round 4
// 240.088 us; speedup vs baseline: 1.1884x; 1.1884x over previous
//
#include <hip/hip_runtime.h>
#include <math.h>

#define IMG 256
#define PIX (IMG * IMG)

// ---------------------------------------------------------------------------
// Mesh renderer forward pass, exact f32 replication of the JAX reference.
// All discrete-decision math (edge functions, barycentrics, z-test) is done
// with contraction OFF and in the reference's association order so that
// inside/valid/z-winner decisions match the numpy reference bit-for-bit.
// R2: k_raster was latency-bound (VALUBusy 8%, 215us) on the serial
// per-survivor global-load chain -> ordered ballot+prefix compaction, LDS
// survivor staging, broadcast walk.
// R3: unconditional barrier schedule (4 __syncthreads per chunk, none inside
// conditionals) to rule out conditional-barrier miscompare as the cause of
// the round-3 core dump. Semantics unchanged vs the passing round-2 kernel.
// ---------------------------------------------------------------------------

// K1: transform + project all vertices; also zero the vertex-normal buffer.
__global__ __launch_bounds__(256) void k_transform(
    const float* __restrict__ verts, const float* __restrict__ tm,
    const float* __restrict__ focal, const float* __restrict__ pp,
    float* __restrict__ vp, float* __restrict__ vn, int B, int V) {
#pragma clang fp contract(off)
    int idx = blockIdx.x * blockDim.x + threadIdx.x;
    if (idx >= B * V) return;
    int b = idx / V;
    const float* tmb = tm + b * 16;
    float x = verts[idx * 3 + 0];
    float y = verts[idx * 3 + 1];
    float z = verts[idx * 3 + 2];
    float vv[3];
    for (int j = 0; j < 3; ++j) {
        // einsum('bvi,bij->bvj'): sum_i v_i * R[i][j], then + T[j]
        float s = x * tmb[0 * 4 + j] + y * tmb[1 * 4 + j];
        s = s + z * tmb[2 * 4 + j];
        vv[j] = s + tmb[j * 4 + 3];
    }
    float f = focal[b];
    float xp = (f * vv[0]) / vv[2] + pp[0];
    float yp = (f * vv[1]) / vv[2] + pp[1];
    vp[idx * 3 + 0] = xp;
    vp[idx * 3 + 1] = yp;
    vp[idx * 3 + 2] = vv[2];
    vn[idx * 3 + 0] = 0.0f;
    vn[idx * 3 + 1] = 0.0f;
    vn[idx * 3 + 2] = 0.0f;
}

// K2: pack per-face screen-space triangle (9 floats) + bbox (4 floats);
// also accumulate world-space face normals into vertex normals (atomics).
__global__ __launch_bounds__(256) void k_pack(
    const float* __restrict__ verts, const int* __restrict__ faces,
    const float* __restrict__ vp, float* __restrict__ packed,
    float* __restrict__ bbox, float* __restrict__ vn,
    int B, int F, int FP, int V) {
#pragma clang fp contract(off)
    int idx = blockIdx.x * blockDim.x + threadIdx.x;
    if (idx >= B * FP) return;
    int b = idx / FP;
    int f = idx - b * FP;
    int i0 = 0, i1 = 0, i2 = 0;
    if (f < F) {
        i0 = faces[f * 3 + 0];
        i1 = faces[f * 3 + 1];
        i2 = faces[f * 3 + 2];
    }
    const float* vpb = vp + (size_t)b * V * 3;
    float x0 = vpb[i0 * 3 + 0], y0 = vpb[i0 * 3 + 1], z0 = vpb[i0 * 3 + 2];
    float x1 = vpb[i1 * 3 + 0], y1 = vpb[i1 * 3 + 1], z1 = vpb[i1 * 3 + 2];
    float x2 = vpb[i2 * 3 + 0], y2 = vpb[i2 * 3 + 1], z2 = vpb[i2 * 3 + 2];
    float* pk = packed + (size_t)idx * 9;
    pk[0] = x0; pk[1] = y0; pk[2] = z0;
    pk[3] = x1; pk[4] = y1; pk[5] = z1;
    pk[6] = x2; pk[7] = y2; pk[8] = z2;
    float4 bb;
    bb.x = fminf(fminf(x0, x1), x2);  // xmin
    bb.y = fmaxf(fmaxf(x0, x1), x2);  // xmax
    bb.z = fminf(fminf(y0, y1), y2);  // ymin
    bb.w = fmaxf(fmaxf(y0, y1), y2);  // ymax
    ((float4*)bbox)[idx] = bb;
    if (f < F) {
        const float* wv = verts + (size_t)b * V * 3;
        float ax = wv[i1 * 3 + 0] - wv[i0 * 3 + 0];
        float ay = wv[i1 * 3 + 1] - wv[i0 * 3 + 1];
        float az = wv[i1 * 3 + 2] - wv[i0 * 3 + 2];
        float bx = wv[i2 * 3 + 0] - wv[i0 * 3 + 0];
        float by = wv[i2 * 3 + 1] - wv[i0 * 3 + 1];
        float bz = wv[i2 * 3 + 2] - wv[i0 * 3 + 2];
        float fnx = ay * bz - az * by;
        float fny = az * bx - ax * bz;
        float fnz = ax * by - ay * bx;
        float* vnb = vn + (size_t)b * V * 3;
        atomicAdd(&vnb[i0 * 3 + 0], fnx);
        atomicAdd(&vnb[i0 * 3 + 1], fny);
        atomicAdd(&vnb[i0 * 3 + 2], fnz);
        atomicAdd(&vnb[i1 * 3 + 0], fnx);
        atomicAdd(&vnb[i1 * 3 + 1], fny);
        atomicAdd(&vnb[i1 * 3 + 2], fnz);
        atomicAdd(&vnb[i2 * 3 + 0], fnx);
        atomicAdd(&vnb[i2 * 3 + 1], fny);
        atomicAdd(&vnb[i2 * 3 + 2], fnz);
    }
}

// K3: normalize vertex normals.
__global__ __launch_bounds__(256) void k_normvn(float* __restrict__ vn, int n) {
#pragma clang fp contract(off)
    int idx = blockIdx.x * blockDim.x + threadIdx.x;
    if (idx >= n) return;
    float x = vn[idx * 3 + 0];
    float y = vn[idx * 3 + 1];
    float z = vn[idx * 3 + 2];
    float nrm = sqrtf((x * x + y * y) + z * z) + 1e-8f;
    vn[idx * 3 + 0] = x / nrm;
    vn[idx * 3 + 1] = y / nrm;
    vn[idx * 3 + 2] = z / nrm;
}

// K4: z-buffer rasterization. One block = one 16x16 pixel tile, one thread
// per pixel. Per 256-face chunk: bbox cull via __ballot, ORDERED compaction
// of survivor ids (popcount prefix, bit order == face order), cooperative
// load of survivor triangles into LDS, then all threads walk the LDS list in
// face order (preserves the reference tie-break: first face attaining the
// minimum z wins). Barrier schedule is unconditional: exactly 4
// __syncthreads() per chunk, never inside a conditional.
__global__ __launch_bounds__(256) void k_raster(
    const float* __restrict__ packed, const float* __restrict__ bbox,
    float* __restrict__ zbuf, int* __restrict__ fidbuf, int FP) {
#pragma clang fp contract(off)
    int b = blockIdx.y;
    int tid = threadIdx.x;
    int tile = blockIdx.x;                   // 0..255, 16x16 tiles
    int tx0 = (tile & 15) * 16;
    int ty0 = (tile >> 4) * 16;
    float px = (float)(tx0 + (tid & 15)) + 0.5f;
    float py = (float)(ty0 + (tid >> 4)) + 0.5f;
    // tile pixel-center range [tx0+0.5, tx0+15.5], margin 0.5px (conservative;
    // f32 edge-function slop is ~1e-4 px).
    float txlo = (float)tx0, txhi = (float)(tx0 + 16);
    float tylo = (float)ty0, tyhi = (float)(ty0 + 16);

    const float* pb = packed + (size_t)b * FP * 9;
    const float4* bb = (const float4*)bbox + (size_t)b * FP;

    float best = INFINITY;
    int bestf = 0;

    __shared__ unsigned long long masks[4];
    __shared__ int slist[256];          // survivor face index within chunk
    __shared__ float sdata[256 * 9];    // survivor triangle data

    int wv = tid >> 6;
    int lane = tid & 63;

    int nchunks = FP / 256;
    float4 bx = bb[tid];                // prefetch chunk 0
    for (int c = 0; c < nchunks; ++c) {
        bool pred = (bx.x <= txhi) && (bx.y >= txlo) &&
                    (bx.z <= tyhi) && (bx.w >= tylo);
        // prefetch next chunk's bbox (hides under compaction+walk)
        if (c + 1 < nchunks) bx = bb[(c + 1) * 256 + tid];
        unsigned long long m = __ballot(pred);
        if (lane == 0) masks[wv] = m;
        __syncthreads();                                   // (1)
        // ordered compaction: rank = survivors before me (face order)
        int base = 0;
        int total = 0;
        for (int i = 0; i < 4; ++i) {
            int pc = __popcll(masks[i]);
            if (i < wv) base += pc;
            total += pc;
        }
        if (pred) {
            int rank = base + __popcll(m & ((1ull << lane) - 1ull));
            slist[rank] = tid;
        }
        __syncthreads();                                   // (2)
        // cooperative load: survivor s's 9 floats -> sdata[s*9 ..]
        // (zero iterations when total == 0)
        int nel = total * 9;
        for (int e = tid; e < nel; e += 256) {
            int s = e / 9;
            int comp = e - s * 9;
            int fl = slist[s];
            sdata[e] = pb[((size_t)(c * 256 + fl)) * 9 + comp];
        }
        __syncthreads();                                   // (3)
        for (int s = 0; s < total; ++s) {
            const float* t = &sdata[s * 9];  // LDS broadcast reads
            float x0 = t[0], y0 = t[1], z0 = t[2];
            float x1 = t[3], y1 = t[4], z1 = t[5];
            float x2 = t[6], y2 = t[7], z2 = t[8];
            // _edge(a,b,p) = (bx-ax)*(py-ay) - (by-ay)*(px-ax)
            float w0 = (x2 - x1) * (py - y1) - (y2 - y1) * (px - x1);
            float w1 = (x0 - x2) * (py - y2) - (y0 - y2) * (px - x2);
            float w2 = (x1 - x0) * (py - y0) - (y1 - y0) * (px - x0);
            float denom = (w0 + w1) + w2;
            bool dok = fabsf(denom) > 1e-8f;
            float safe = dok ? denom : 1.0f;
            float b0 = w0 / safe;
            float b1 = w1 / safe;
            float b2 = w2 / safe;
            float zint = (b0 * z0 + b1 * z1) + b2 * z2;
            bool inside = (b0 >= 0.0f) && (b1 >= 0.0f) && (b2 >= 0.0f) &&
                          dok && (zint > 1e-4f);
            if (inside && zint < best) {
                best = zint;
                bestf = c * 256 + slist[s];
            }
        }
        __syncthreads();                                   // (4)
    }
    int p = (ty0 + (tid >> 4)) * IMG + tx0 + (tid & 15);
    zbuf[(size_t)b * PIX + p] = best;
    fidbuf[(size_t)b * PIX + p] = bestf;
}

// K5: shading. Recompute barycentrics for the winning face exactly as the
// reference does, gather world positions / vertex normals, Phong.
__global__ __launch_bounds__(256) void k_shade(
    const float* __restrict__ verts, const int* __restrict__ faces,
    const float* __restrict__ tm, const float* __restrict__ packed,
    const float* __restrict__ vn, const float* __restrict__ zbuf,
    const int* __restrict__ fidbuf, float* __restrict__ out,
    int B, int V, int FP) {
#pragma clang fp contract(off)
    int p = blockIdx.x * blockDim.x + threadIdx.x;
    int b = blockIdx.y;
    if (p >= PIX) return;
    size_t imgbase = (size_t)b * 3 * PIX;
    size_t alphabase = (size_t)B * 3 * PIX + (size_t)b * PIX;
    float z = zbuf[(size_t)b * PIX + p];
    if (!isfinite(z)) {
        out[imgbase + 0 * PIX + p] = 255.0f;
        out[imgbase + 1 * PIX + p] = 255.0f;
        out[imgbase + 2 * PIX + p] = 255.0f;
        out[alphabase + p] = 0.0f;
        return;
    }
    int f = fidbuf[(size_t)b * PIX + p];
    float px = (float)(p & (IMG - 1)) + 0.5f;
    float py = (float)(p >> 8) + 0.5f;
    const float* t = packed + ((size_t)b * FP + f) * 9;
    float x0 = t[0], y0 = t[1];
    float x1 = t[3], y1 = t[4];
    float x2 = t[6], y2 = t[7];
    float w0 = (x2 - x1) * (py - y1) - (y2 - y1) * (px - x1);
    float w1 = (x0 - x2) * (py - y2) - (y0 - y2) * (px - x2);
    float w2 = (x1 - x0) * (py - y0) - (y1 - y0) * (px - x0);
    float denom = (w0 + w1) + w2;
    float safe = (fabsf(denom) > 1e-8f) ? denom : 1.0f;
    float b0 = w0 / safe;
    float b1 = w1 / safe;
    float b2 = w2 / safe;

    int i0 = faces[f * 3 + 0];
    int i1 = faces[f * 3 + 1];
    int i2 = faces[f * 3 + 2];
    const float* wv = verts + (size_t)b * V * 3;
    const float* vnb = vn + (size_t)b * V * 3;

    float pos[3], nr[3];
    for (int c = 0; c < 3; ++c) {
        pos[c] = (b0 * wv[i0 * 3 + c] + b1 * wv[i1 * 3 + c]) + b2 * wv[i2 * 3 + c];
        nr[c]  = (b0 * vnb[i0 * 3 + c] + b1 * vnb[i1 * 3 + c]) + b2 * vnb[i2 * 3 + c];
    }
    float nl = sqrtf((nr[0] * nr[0] + nr[1] * nr[1]) + nr[2] * nr[2]) + 1e-8f;
    nr[0] = nr[0] / nl; nr[1] = nr[1] / nl; nr[2] = nr[2] / nl;

    // cam_i = -sum_j T_j * R[i][j]
    const float* tmb = tm + b * 16;
    float T0 = tmb[3], T1 = tmb[7], T2 = tmb[11];
    float cam[3];
    for (int i = 0; i < 3; ++i)
        cam[i] = -((T0 * tmb[i * 4 + 0] + T1 * tmb[i * 4 + 1]) + T2 * tmb[i * 4 + 2]);

    // L = normalize(light - pos), light = (0,0,3)
    float Lx = 0.0f - pos[0], Ly = 0.0f - pos[1], Lz = 3.0f - pos[2];
    float Ln = sqrtf((Lx * Lx + Ly * Ly) + Lz * Lz) + 1e-8f;
    Lx = Lx / Ln; Ly = Ly / Ln; Lz = Lz / Ln;
    // Vd = normalize(cam - pos)
    float Vx = cam[0] - pos[0], Vy = cam[1] - pos[1], Vz = cam[2] - pos[2];
    float Vn2 = sqrtf((Vx * Vx + Vy * Vy) + Vz * Vz) + 1e-8f;
    Vx = Vx / Vn2; Vy = Vy / Vn2; Vz = Vz / Vn2;

    float ndl = (nr[0] * Lx + nr[1] * Ly) + nr[2] * Lz;
    float t2 = 2.0f * ndl;
    float rx = (t2 * nr[0]) - Lx;
    float ry = (t2 * nr[1]) - Ly;
    float rz = (t2 * nr[2]) - Lz;
    float rv = (rx * Vx + ry * Vy) + rz * Vz;
    float sp = powf(fmaxf(rv, 0.0f), 64.0f);
    float spec = (0.2f * sp) * ((ndl > 0.0f) ? 1.0f : 0.0f);
    float col = (0.5f + 0.3f * fmaxf(ndl, 0.0f)) + spec;
    col = col * 255.0f;
    out[imgbase + 0 * PIX + p] = col;
    out[imgbase + 1 * PIX + p] = col;
    out[imgbase + 2 * PIX + p] = col;
    out[alphabase + p] = 1.0f;
}

extern "C" void kernel_launch(void* const* d_in, const int* in_sizes, int n_in,
                              void* d_out, int out_size, void* d_ws, size_t ws_size,
                              hipStream_t stream) {
    const float* verts = (const float*)d_in[0];
    const float* tm    = (const float*)d_in[1];
    const float* focal = (const float*)d_in[2];
    const float* pp    = (const float*)d_in[3];
    const int*   faces = (const int*)d_in[4];

    int B = in_sizes[1] / 16;
    int V = in_sizes[0] / (3 * B);
    int F = in_sizes[4] / 3;
    int FP = ((F + 255) / 256) * 256;  // pad to chunk multiple; pads are inert

    float* out = (float*)d_out;

    // workspace layout (floats)
    float* vp     = (float*)d_ws;            // B*V*3
    float* vn     = vp + (size_t)B * V * 3;  // B*V*3
    float* packed = vn + (size_t)B * V * 3;  // B*FP*9
    float* bbox   = packed + (size_t)B * FP * 9;  // B*FP*4 (16B aligned)
    float* zbuf   = bbox + (size_t)B * FP * 4;    // B*PIX
    int*   fid    = (int*)(zbuf + (size_t)B * PIX);  // B*PIX

    int nv = B * V;
    k_transform<<<dim3((nv + 255) / 256), dim3(256), 0, stream>>>(
        verts, tm, focal, pp, vp, vn, B, V);
    k_pack<<<dim3((B * FP + 255) / 256), dim3(256), 0, stream>>>(
        verts, faces, vp, packed, bbox, vn, B, F, FP, V);
    k_normvn<<<dim3((nv + 255) / 256), dim3(256), 0, stream>>>(vn, nv);
    k_raster<<<dim3(256, B), dim3(256), 0, stream>>>(packed, bbox, zbuf, fid, FP);
    k_shade<<<dim3(PIX / 256, B), dim3(256), 0, stream>>>(
        verts, faces, tm, packed, vn, zbuf, fid, out, B, V, FP);
}

// Round 5
// 175.685 us; speedup vs baseline: 1.6241x; 1.3666x over previous
//
#include <hip/hip_runtime.h>
#include <math.h>

#define IMG 256
#define PIX (IMG * IMG)
#define SENT 0xFFFFFFFFFFFFFFFFull

// ---------------------------------------------------------------------------
// Mesh renderer forward pass, exact f32 replication of the JAX reference.
// All discrete-decision math (edge functions, barycentrics, z-test) is done
// with contraction OFF and in the reference's association order so that
// inside/valid/z-winner decisions match the numpy reference bit-for-bit.
// R4: the reference's chunked scan+argmin+strict< update is EXACTLY
// argmin(z, tie -> lowest face id). So rasterization is order-free:
// pack (z_bits<<32 | fid) into u64 (z>1e-4 => positive => IEEE bit order
// == float order; lexicographic tie == min fid) and combine via atomicMin.
// This removes the serial 40-chunk walk that left the old kernel
// latency-bound (169us, 4.6% occupancy): now 4096 blocks (tiles x
// face-groups x B) walk independent face slices in parallel.
// ---------------------------------------------------------------------------

// K1: transform + project all vertices; also zero the vertex-normal buffer.
__global__ __launch_bounds__(256) void k_transform(
    const float* __restrict__ verts, const float* __restrict__ tm,
    const float* __restrict__ focal, const float* __restrict__ pp,
    float* __restrict__ vp, float* __restrict__ vn, int B, int V) {
#pragma clang fp contract(off)
    int idx = blockIdx.x * blockDim.x + threadIdx.x;
    if (idx >= B * V) return;
    int b = idx / V;
    const float* tmb = tm + b * 16;
    float x = verts[idx * 3 + 0];
    float y = verts[idx * 3 + 1];
    float z = verts[idx * 3 + 2];
    float vv[3];
    for (int j = 0; j < 3; ++j) {
        // einsum('bvi,bij->bvj'): sum_i v_i * R[i][j], then + T[j]
        float s = x * tmb[0 * 4 + j] + y * tmb[1 * 4 + j];
        s = s + z * tmb[2 * 4 + j];
        vv[j] = s + tmb[j * 4 + 3];
    }
    float f = focal[b];
    float xp = (f * vv[0]) / vv[2] + pp[0];
    float yp = (f * vv[1]) / vv[2] + pp[1];
    vp[idx * 3 + 0] = xp;
    vp[idx * 3 + 1] = yp;
    vp[idx * 3 + 2] = vv[2];
    vn[idx * 3 + 0] = 0.0f;
    vn[idx * 3 + 1] = 0.0f;
    vn[idx * 3 + 2] = 0.0f;
}

// K2: pack per-face screen-space triangle (9 floats) + bbox (4 floats);
// also accumulate world-space face normals into vertex normals (atomics).
__global__ __launch_bounds__(256) void k_pack(
    const float* __restrict__ verts, const int* __restrict__ faces,
    const float* __restrict__ vp, float* __restrict__ packed,
    float* __restrict__ bbox, float* __restrict__ vn,
    int B, int F, int FP, int V) {
#pragma clang fp contract(off)
    int idx = blockIdx.x * blockDim.x + threadIdx.x;
    if (idx >= B * FP) return;
    int b = idx / FP;
    int f = idx - b * FP;
    int i0 = 0, i1 = 0, i2 = 0;
    if (f < F) {
        i0 = faces[f * 3 + 0];
        i1 = faces[f * 3 + 1];
        i2 = faces[f * 3 + 2];
    }
    const float* vpb = vp + (size_t)b * V * 3;
    float x0 = vpb[i0 * 3 + 0], y0 = vpb[i0 * 3 + 1], z0 = vpb[i0 * 3 + 2];
    float x1 = vpb[i1 * 3 + 0], y1 = vpb[i1 * 3 + 1], z1 = vpb[i1 * 3 + 2];
    float x2 = vpb[i2 * 3 + 0], y2 = vpb[i2 * 3 + 1], z2 = vpb[i2 * 3 + 2];
    float* pk = packed + (size_t)idx * 9;
    pk[0] = x0; pk[1] = y0; pk[2] = z0;
    pk[3] = x1; pk[4] = y1; pk[5] = z1;
    pk[6] = x2; pk[7] = y2; pk[8] = z2;
    float4 bb;
    bb.x = fminf(fminf(x0, x1), x2);  // xmin
    bb.y = fmaxf(fmaxf(x0, x1), x2);  // xmax
    bb.z = fminf(fminf(y0, y1), y2);  // ymin
    bb.w = fmaxf(fmaxf(y0, y1), y2);  // ymax
    ((float4*)bbox)[idx] = bb;
    if (f < F) {
        const float* wv = verts + (size_t)b * V * 3;
        float ax = wv[i1 * 3 + 0] - wv[i0 * 3 + 0];
        float ay = wv[i1 * 3 + 1] - wv[i0 * 3 + 1];
        float az = wv[i1 * 3 + 2] - wv[i0 * 3 + 2];
        float bx = wv[i2 * 3 + 0] - wv[i0 * 3 + 0];
        float by = wv[i2 * 3 + 1] - wv[i0 * 3 + 1];
        float bz = wv[i2 * 3 + 2] - wv[i0 * 3 + 2];
        float fnx = ay * bz - az * by;
        float fny = az * bx - ax * bz;
        float fnz = ax * by - ay * bx;
        float* vnb = vn + (size_t)b * V * 3;
        atomicAdd(&vnb[i0 * 3 + 0], fnx);
        atomicAdd(&vnb[i0 * 3 + 1], fny);
        atomicAdd(&vnb[i0 * 3 + 2], fnz);
        atomicAdd(&vnb[i1 * 3 + 0], fnx);
        atomicAdd(&vnb[i1 * 3 + 1], fny);
        atomicAdd(&vnb[i1 * 3 + 2], fnz);
        atomicAdd(&vnb[i2 * 3 + 0], fnx);
        atomicAdd(&vnb[i2 * 3 + 1], fny);
        atomicAdd(&vnb[i2 * 3 + 2], fnz);
    }
}

// K3: normalize vertex normals.
__global__ __launch_bounds__(256) void k_normvn(float* __restrict__ vn, int n) {
#pragma clang fp contract(off)
    int idx = blockIdx.x * blockDim.x + threadIdx.x;
    if (idx >= n) return;
    float x = vn[idx * 3 + 0];
    float y = vn[idx * 3 + 1];
    float z = vn[idx * 3 + 2];
    float nrm = sqrtf((x * x + y * y) + z * z) + 1e-8f;
    vn[idx * 3 + 0] = x / nrm;
    vn[idx * 3 + 1] = y / nrm;
    vn[idx * 3 + 2] = z / nrm;
}

// K4: parallel rasterization. Block = (16x16 pixel tile) x (one group of
// CPG*256 faces) x batch. Cull via bbox + unordered LDS-atomic compaction,
// cooperative gather of survivors into LDS, walk, then one u64 atomicMin
// per pixel. Packing (z_bits<<32)|fid makes min() == argmin(z, tie->min
// fid) == the reference's selection rule, independent of order.
#define CPG 5  // 256-face chunks per group
__global__ __launch_bounds__(256) void k_raster(
    const float* __restrict__ packed, const float* __restrict__ bbox,
    unsigned long long* __restrict__ zpk, int FP) {
#pragma clang fp contract(off)
    int b = blockIdx.z;
    int tid = threadIdx.x;
    int tile = blockIdx.x;                   // 0..255, 16x16 tiles
    int tx0 = (tile & 15) * 16;
    int ty0 = (tile >> 4) * 16;
    float px = (float)(tx0 + (tid & 15)) + 0.5f;
    float py = (float)(ty0 + (tid >> 4)) + 0.5f;
    // tile pixel-center range [tx0+0.5, tx0+15.5], margin 0.5px (conservative;
    // f32 edge-function slop is ~1e-4 px).
    float txlo = (float)tx0, txhi = (float)(tx0 + 16);
    float tylo = (float)ty0, tyhi = (float)(ty0 + 16);

    const float* pb = packed + (size_t)b * FP * 9;
    const float4* bb = (const float4*)bbox + (size_t)b * FP;

    unsigned long long best = SENT;

    __shared__ int slist[256];          // survivor global face ids (unordered)
    __shared__ float sdata[256 * 9];    // survivor triangle data
    __shared__ int scnt;

    int gbase = blockIdx.y * (CPG * 256);
    for (int c = 0; c < CPG; ++c) {
        int fidx = gbase + c * 256 + tid;
        if (tid == 0) scnt = 0;
        __syncthreads();                                   // (1) scnt ready
        bool pred = false;
        if (fidx < FP) {
            float4 bx = bb[fidx];
            pred = (bx.x <= txhi) && (bx.y >= txlo) &&
                   (bx.z <= tyhi) && (bx.w >= tylo);
        }
        if (pred) {
            int r = atomicAdd(&scnt, 1);
            slist[r] = fidx;
        }
        __syncthreads();                                   // (2) list ready
        int cnt = scnt;
        // cooperative gather: survivor s's 9 floats -> sdata[s*9 ..]
        for (int e = tid; e < cnt * 9; e += 256) {
            int s = e / 9;
            int comp = e - s * 9;
            sdata[e] = pb[(size_t)slist[s] * 9 + comp];
        }
        __syncthreads();                                   // (3) data ready
        for (int s = 0; s < cnt; ++s) {
            const float* t = &sdata[s * 9];  // LDS broadcast reads
            float x0 = t[0], y0 = t[1], z0 = t[2];
            float x1 = t[3], y1 = t[4], z1 = t[5];
            float x2 = t[6], y2 = t[7], z2 = t[8];
            // _edge(a,b,p) = (bx-ax)*(py-ay) - (by-ay)*(px-ax)
            float w0 = (x2 - x1) * (py - y1) - (y2 - y1) * (px - x1);
            float w1 = (x0 - x2) * (py - y2) - (y0 - y2) * (px - x2);
            float w2 = (x1 - x0) * (py - y0) - (y1 - y0) * (px - x0);
            float denom = (w0 + w1) + w2;
            bool dok = fabsf(denom) > 1e-8f;
            float safe = dok ? denom : 1.0f;
            float b0 = w0 / safe;
            float b1 = w1 / safe;
            float b2 = w2 / safe;
            float zint = (b0 * z0 + b1 * z1) + b2 * z2;
            bool inside = (b0 >= 0.0f) && (b1 >= 0.0f) && (b2 >= 0.0f) &&
                          dok && (zint > 1e-4f);
            if (inside) {
                unsigned long long cand =
                    ((unsigned long long)__float_as_uint(zint) << 32) |
                    (unsigned int)slist[s];
                if (cand < best) best = cand;
            }
        }
        __syncthreads();                                   // (4) reuse guard
    }
    if (best != SENT) {
        int p = (ty0 + (tid >> 4)) * IMG + tx0 + (tid & 15);
        atomicMin(&zpk[(size_t)b * PIX + p], best);
    }
}

// K5: shading. Recompute barycentrics for the winning face exactly as the
// reference does, gather world positions / vertex normals, Phong.
__global__ __launch_bounds__(256) void k_shade(
    const float* __restrict__ verts, const int* __restrict__ faces,
    const float* __restrict__ tm, const float* __restrict__ packed,
    const float* __restrict__ vn, const unsigned long long* __restrict__ zpk,
    float* __restrict__ out, int B, int V, int FP) {
#pragma clang fp contract(off)
    int p = blockIdx.x * blockDim.x + threadIdx.x;
    int b = blockIdx.y;
    if (p >= PIX) return;
    size_t imgbase = (size_t)b * 3 * PIX;
    size_t alphabase = (size_t)B * 3 * PIX + (size_t)b * PIX;
    unsigned long long v = zpk[(size_t)b * PIX + p];
    if (v == SENT) {
        out[imgbase + 0 * PIX + p] = 255.0f;
        out[imgbase + 1 * PIX + p] = 255.0f;
        out[imgbase + 2 * PIX + p] = 255.0f;
        out[alphabase + p] = 0.0f;
        return;
    }
    int f = (int)(v & 0xFFFFFFFFull);
    float px = (float)(p & (IMG - 1)) + 0.5f;
    float py = (float)(p >> 8) + 0.5f;
    const float* t = packed + ((size_t)b * FP + f) * 9;
    float x0 = t[0], y0 = t[1];
    float x1 = t[3], y1 = t[4];
    float x2 = t[6], y2 = t[7];
    float w0 = (x2 - x1) * (py - y1) - (y2 - y1) * (px - x1);
    float w1 = (x0 - x2) * (py - y2) - (y0 - y2) * (px - x2);
    float w2 = (x1 - x0) * (py - y0) - (y1 - y0) * (px - x0);
    float denom = (w0 + w1) + w2;
    float safe = (fabsf(denom) > 1e-8f) ? denom : 1.0f;
    float b0 = w0 / safe;
    float b1 = w1 / safe;
    float b2 = w2 / safe;

    int i0 = faces[f * 3 + 0];
    int i1 = faces[f * 3 + 1];
    int i2 = faces[f * 3 + 2];
    const float* wv = verts + (size_t)b * V * 3;
    const float* vnb = vn + (size_t)b * V * 3;

    float pos[3], nr[3];
    for (int c = 0; c < 3; ++c) {
        pos[c] = (b0 * wv[i0 * 3 + c] + b1 * wv[i1 * 3 + c]) + b2 * wv[i2 * 3 + c];
        nr[c]  = (b0 * vnb[i0 * 3 + c] + b1 * vnb[i1 * 3 + c]) + b2 * vnb[i2 * 3 + c];
    }
    float nl = sqrtf((nr[0] * nr[0] + nr[1] * nr[1]) + nr[2] * nr[2]) + 1e-8f;
    nr[0] = nr[0] / nl; nr[1] = nr[1] / nl; nr[2] = nr[2] / nl;

    // cam_i = -sum_j T_j * R[i][j]
    const float* tmb = tm + b * 16;
    float T0 = tmb[3], T1 = tmb[7], T2 = tmb[11];
    float cam[3];
    for (int i = 0; i < 3; ++i)
        cam[i] = -((T0 * tmb[i * 4 + 0] + T1 * tmb[i * 4 + 1]) + T2 * tmb[i * 4 + 2]);

    // L = normalize(light - pos), light = (0,0,3)
    float Lx = 0.0f - pos[0], Ly = 0.0f - pos[1], Lz = 3.0f - pos[2];
    float Ln = sqrtf((Lx * Lx + Ly * Ly) + Lz * Lz) + 1e-8f;
    Lx = Lx / Ln; Ly = Ly / Ln; Lz = Lz / Ln;
    // Vd = normalize(cam - pos)
    float Vx = cam[0] - pos[0], Vy = cam[1] - pos[1], Vz = cam[2] - pos[2];
    float Vn2 = sqrtf((Vx * Vx + Vy * Vy) + Vz * Vz) + 1e-8f;
    Vx = Vx / Vn2; Vy = Vy / Vn2; Vz = Vz / Vn2;

    float ndl = (nr[0] * Lx + nr[1] * Ly) + nr[2] * Lz;
    float t2 = 2.0f * ndl;
    float rx = (t2 * nr[0]) - Lx;
    float ry = (t2 * nr[1]) - Ly;
    float rz = (t2 * nr[2]) - Lz;
    float rv = (rx * Vx + ry * Vy) + rz * Vz;
    float sp = powf(fmaxf(rv, 0.0f), 64.0f);
    float spec = (0.2f * sp) * ((ndl > 0.0f) ? 1.0f : 0.0f);
    float col = (0.5f + 0.3f * fmaxf(ndl, 0.0f)) + spec;
    col = col * 255.0f;
    out[imgbase + 0 * PIX + p] = col;
    out[imgbase + 1 * PIX + p] = col;
    out[imgbase + 2 * PIX + p] = col;
    out[alphabase + p] = 1.0f;
}

extern "C" void kernel_launch(void* const* d_in, const int* in_sizes, int n_in,
                              void* d_out, int out_size, void* d_ws, size_t ws_size,
                              hipStream_t stream) {
    const float* verts = (const float*)d_in[0];
    const float* tm    = (const float*)d_in[1];
    const float* focal = (const float*)d_in[2];
    const float* pp    = (const float*)d_in[3];
    const int*   faces = (const int*)d_in[4];

    int B = in_sizes[1] / 16;
    int V = in_sizes[0] / (3 * B);
    int F = in_sizes[4] / 3;
    int FP = ((F + 255) / 256) * 256;  // pad to chunk multiple; pads are inert

    float* out = (float*)d_out;

    // workspace layout (floats; zpk offset is 8-byte aligned: even float count)
    float* vp     = (float*)d_ws;            // B*V*3
    float* vn     = vp + (size_t)B * V * 3;  // B*V*3
    float* packed = vn + (size_t)B * V * 3;  // B*FP*9
    float* bbox   = packed + (size_t)B * FP * 9;       // B*FP*4 (16B aligned)
    unsigned long long* zpk =
        (unsigned long long*)(bbox + (size_t)B * FP * 4);  // B*PIX u64

    int nv = B * V;
    hipMemsetAsync(zpk, 0xFF, (size_t)B * PIX * 8, stream);  // all-ones = SENT
    k_transform<<<dim3((nv + 255) / 256), dim3(256), 0, stream>>>(
        verts, tm, focal, pp, vp, vn, B, V);
    k_pack<<<dim3((B * FP + 255) / 256), dim3(256), 0, stream>>>(
        verts, faces, vp, packed, bbox, vn, B, F, FP, V);
    k_normvn<<<dim3((nv + 255) / 256), dim3(256), 0, stream>>>(vn, nv);
    int ngroups = (FP + CPG * 256 - 1) / (CPG * 256);
    k_raster<<<dim3(256, ngroups, B), dim3(256), 0, stream>>>(
        packed, bbox, zpk, FP);
    k_shade<<<dim3(PIX / 256, B), dim3(256), 0, stream>>>(
        verts, faces, tm, packed, vn, zpk, out, B, V, FP);
}

// Round 6
// 79.593 us; speedup vs baseline: 3.5849x; 2.2073x over previous
//
#include <hip/hip_runtime.h>
#include <math.h>

#define IMG 256
#define PIX (IMG * IMG)
#define SENT 0xFFFFFFFFFFFFFFFFull

// ---------------------------------------------------------------------------
// Mesh renderer forward pass, exact f32 replication of the JAX reference.
// All discrete-decision math (edge functions, barycentrics, z-test) is done
// with contraction OFF and in the reference's association order so that
// inside/valid/z-winner decisions match the numpy reference bit-for-bit.
// R4: winner selection == argmin(z, tie->lowest fid) == u64 atomicMin of
// (z_bits<<32)|fid (z>1e-4 -> IEEE bit order == float order). Order-free.
// R5: tile-gather raster was STILL latency-bound (125us, VALUBusy 13.6%,
// occupancy 10%): serial per-block chunk chain + dense-tile imbalance tail.
// Invert to SCATTER: one wave per face; lanes sweep the face's pixel bbox
// and atomicMin inside pixels. No LDS, no barriers, no imbalance. min() is
// idempotent so over-margin / duplicate tests are harmless.
// Also: zpk init folded into k_transform (drop memset dispatch); vertex-
// normal normalization folded into k_shade (drop k_normvn dispatch).
// ---------------------------------------------------------------------------

// K1: transform + project all vertices; zero vn; init zpk sentinel.
__global__ __launch_bounds__(256) void k_transform(
    const float* __restrict__ verts, const float* __restrict__ tm,
    const float* __restrict__ focal, const float* __restrict__ pp,
    float* __restrict__ vp, float* __restrict__ vn,
    unsigned long long* __restrict__ zpk, int B, int V) {
#pragma clang fp contract(off)
    int idx = blockIdx.x * blockDim.x + threadIdx.x;
    int nthreads = gridDim.x * blockDim.x;
    // grid-stride sentinel fill of zpk (B*PIX u64)
    for (int i = idx; i < B * PIX; i += nthreads) zpk[i] = SENT;
    if (idx >= B * V) return;
    int b = idx / V;
    const float* tmb = tm + b * 16;
    float x = verts[idx * 3 + 0];
    float y = verts[idx * 3 + 1];
    float z = verts[idx * 3 + 2];
    float vv[3];
    for (int j = 0; j < 3; ++j) {
        // einsum('bvi,bij->bvj'): sum_i v_i * R[i][j], then + T[j]
        float s = x * tmb[0 * 4 + j] + y * tmb[1 * 4 + j];
        s = s + z * tmb[2 * 4 + j];
        vv[j] = s + tmb[j * 4 + 3];
    }
    float f = focal[b];
    float xp = (f * vv[0]) / vv[2] + pp[0];
    float yp = (f * vv[1]) / vv[2] + pp[1];
    vp[idx * 3 + 0] = xp;
    vp[idx * 3 + 1] = yp;
    vp[idx * 3 + 2] = vv[2];
    vn[idx * 3 + 0] = 0.0f;
    vn[idx * 3 + 1] = 0.0f;
    vn[idx * 3 + 2] = 0.0f;
}

// K2: pack per-face screen-space triangle (9 floats); accumulate world-space
// face normals into vertex normals (atomics).
__global__ __launch_bounds__(256) void k_pack(
    const float* __restrict__ verts, const int* __restrict__ faces,
    const float* __restrict__ vp, float* __restrict__ packed,
    float* __restrict__ vn, int B, int F, int FP, int V) {
#pragma clang fp contract(off)
    int idx = blockIdx.x * blockDim.x + threadIdx.x;
    if (idx >= B * FP) return;
    int b = idx / FP;
    int f = idx - b * FP;
    int i0 = 0, i1 = 0, i2 = 0;
    if (f < F) {
        i0 = faces[f * 3 + 0];
        i1 = faces[f * 3 + 1];
        i2 = faces[f * 3 + 2];
    }
    const float* vpb = vp + (size_t)b * V * 3;
    float* pk = packed + (size_t)idx * 9;
    pk[0] = vpb[i0 * 3 + 0]; pk[1] = vpb[i0 * 3 + 1]; pk[2] = vpb[i0 * 3 + 2];
    pk[3] = vpb[i1 * 3 + 0]; pk[4] = vpb[i1 * 3 + 1]; pk[5] = vpb[i1 * 3 + 2];
    pk[6] = vpb[i2 * 3 + 0]; pk[7] = vpb[i2 * 3 + 1]; pk[8] = vpb[i2 * 3 + 2];
    if (f < F) {
        const float* wv = verts + (size_t)b * V * 3;
        float ax = wv[i1 * 3 + 0] - wv[i0 * 3 + 0];
        float ay = wv[i1 * 3 + 1] - wv[i0 * 3 + 1];
        float az = wv[i1 * 3 + 2] - wv[i0 * 3 + 2];
        float bx = wv[i2 * 3 + 0] - wv[i0 * 3 + 0];
        float by = wv[i2 * 3 + 1] - wv[i0 * 3 + 1];
        float bz = wv[i2 * 3 + 2] - wv[i0 * 3 + 2];
        float fnx = ay * bz - az * by;
        float fny = az * bx - ax * bz;
        float fnz = ax * by - ay * bx;
        float* vnb = vn + (size_t)b * V * 3;
        atomicAdd(&vnb[i0 * 3 + 0], fnx);
        atomicAdd(&vnb[i0 * 3 + 1], fny);
        atomicAdd(&vnb[i0 * 3 + 2], fnz);
        atomicAdd(&vnb[i1 * 3 + 0], fnx);
        atomicAdd(&vnb[i1 * 3 + 1], fny);
        atomicAdd(&vnb[i1 * 3 + 2], fnz);
        atomicAdd(&vnb[i2 * 3 + 0], fnx);
        atomicAdd(&vnb[i2 * 3 + 1], fny);
        atomicAdd(&vnb[i2 * 3 + 2], fnz);
    }
}

// K4: scatter rasterization, one WAVE per face. Lanes sweep the face's
// (conservatively margined, clamped) pixel bbox; inside pixels do a u64
// atomicMin of (z_bits<<32)|fid. Identical per-pixel arithmetic to the
// reference; min is order-free and idempotent.
__global__ __launch_bounds__(256) void k_raster(
    const float* __restrict__ packed,
    unsigned long long* __restrict__ zpk, int FP) {
#pragma clang fp contract(off)
    int b = blockIdx.y;
    int wid = threadIdx.x >> 6;
    int lane = threadIdx.x & 63;
    int f = blockIdx.x * 4 + wid;
    if (f >= FP) return;

    const float* t = packed + ((size_t)b * FP + f) * 9;  // broadcast loads
    float x0 = t[0], y0 = t[1], z0 = t[2];
    float x1 = t[3], y1 = t[4], z1 = t[5];
    float x2 = t[6], y2 = t[7], z2 = t[8];

    float xmin = fminf(fminf(x0, x1), x2);
    float xmax = fmaxf(fmaxf(x0, x1), x2);
    float ymin = fminf(fminf(y0, y1), y2);
    float ymax = fmaxf(fmaxf(y0, y1), y2);

    // pixel centers are ix+0.5; conservative bounds with >=0.5px margin vs
    // ~1e-2px worst-case f32 edge slop, clamped to the image.
    int ix0 = (int)floorf(xmin - 0.5f); ix0 = ix0 < 0 ? 0 : ix0;
    int iy0 = (int)floorf(ymin - 0.5f); iy0 = iy0 < 0 ? 0 : iy0;
    int ix1 = (int)ceilf(xmax - 0.5f);  ix1 = ix1 > IMG - 1 ? IMG - 1 : ix1;
    int iy1 = (int)ceilf(ymax - 0.5f);  iy1 = iy1 > IMG - 1 ? IMG - 1 : iy1;
    int w = ix1 - ix0 + 1;
    int h = iy1 - iy0 + 1;
    if (w <= 0 || h <= 0) return;
    int n = w * h;

    unsigned long long* zb = zpk + (size_t)b * PIX;
    for (int i = lane; i < n; i += 64) {
        int iy = (int)((unsigned)i / (unsigned)w);
        int ix = i - iy * w;
        float px = (float)(ix0 + ix) + 0.5f;
        float py = (float)(iy0 + iy) + 0.5f;
        // _edge(a,b,p) = (bx-ax)*(py-ay) - (by-ay)*(px-ax)
        float w0 = (x2 - x1) * (py - y1) - (y2 - y1) * (px - x1);
        float w1 = (x0 - x2) * (py - y2) - (y0 - y2) * (px - x2);
        float w2 = (x1 - x0) * (py - y0) - (y1 - y0) * (px - x0);
        float denom = (w0 + w1) + w2;
        bool dok = fabsf(denom) > 1e-8f;
        float safe = dok ? denom : 1.0f;
        float b0 = w0 / safe;
        float b1 = w1 / safe;
        float b2 = w2 / safe;
        float zint = (b0 * z0 + b1 * z1) + b2 * z2;
        bool inside = (b0 >= 0.0f) && (b1 >= 0.0f) && (b2 >= 0.0f) &&
                      dok && (zint > 1e-4f);
        if (inside) {
            unsigned long long cand =
                ((unsigned long long)__float_as_uint(zint) << 32) |
                (unsigned int)f;
            atomicMin(&zb[(iy0 + iy) * IMG + (ix0 + ix)], cand);
        }
    }
}

// K5: shading. Recompute barycentrics for the winning face exactly as the
// reference does; normalize gathered vertex normals inline (identical ops
// to the former k_normvn); Phong.
__global__ __launch_bounds__(256) void k_shade(
    const float* __restrict__ verts, const int* __restrict__ faces,
    const float* __restrict__ tm, const float* __restrict__ packed,
    const float* __restrict__ vn, const unsigned long long* __restrict__ zpk,
    float* __restrict__ out, int B, int V, int FP) {
#pragma clang fp contract(off)
    int p = blockIdx.x * blockDim.x + threadIdx.x;
    int b = blockIdx.y;
    if (p >= PIX) return;
    size_t imgbase = (size_t)b * 3 * PIX;
    size_t alphabase = (size_t)B * 3 * PIX + (size_t)b * PIX;
    unsigned long long v = zpk[(size_t)b * PIX + p];
    if (v == SENT) {
        out[imgbase + 0 * PIX + p] = 255.0f;
        out[imgbase + 1 * PIX + p] = 255.0f;
        out[imgbase + 2 * PIX + p] = 255.0f;
        out[alphabase + p] = 0.0f;
        return;
    }
    int f = (int)(v & 0xFFFFFFFFull);
    float px = (float)(p & (IMG - 1)) + 0.5f;
    float py = (float)(p >> 8) + 0.5f;
    const float* t = packed + ((size_t)b * FP + f) * 9;
    float x0 = t[0], y0 = t[1];
    float x1 = t[3], y1 = t[4];
    float x2 = t[6], y2 = t[7];
    float w0 = (x2 - x1) * (py - y1) - (y2 - y1) * (px - x1);
    float w1 = (x0 - x2) * (py - y2) - (y0 - y2) * (px - x2);
    float w2 = (x1 - x0) * (py - y0) - (y1 - y0) * (px - x0);
    float denom = (w0 + w1) + w2;
    float safe = (fabsf(denom) > 1e-8f) ? denom : 1.0f;
    float b0 = w0 / safe;
    float b1 = w1 / safe;
    float b2 = w2 / safe;

    int i0 = faces[f * 3 + 0];
    int i1 = faces[f * 3 + 1];
    int i2 = faces[f * 3 + 2];
    const float* wv = verts + (size_t)b * V * 3;
    const float* vnb = vn + (size_t)b * V * 3;

    // inline vertex-normal normalization (identical ops to old k_normvn)
    float a0 = vnb[i0 * 3 + 0], a1 = vnb[i0 * 3 + 1], a2 = vnb[i0 * 3 + 2];
    float c0 = vnb[i1 * 3 + 0], c1 = vnb[i1 * 3 + 1], c2 = vnb[i1 * 3 + 2];
    float d0 = vnb[i2 * 3 + 0], d1 = vnb[i2 * 3 + 1], d2 = vnb[i2 * 3 + 2];
    float na = sqrtf((a0 * a0 + a1 * a1) + a2 * a2) + 1e-8f;
    float nc = sqrtf((c0 * c0 + c1 * c1) + c2 * c2) + 1e-8f;
    float nd = sqrtf((d0 * d0 + d1 * d1) + d2 * d2) + 1e-8f;
    a0 = a0 / na; a1 = a1 / na; a2 = a2 / na;
    c0 = c0 / nc; c1 = c1 / nc; c2 = c2 / nc;
    d0 = d0 / nd; d1 = d1 / nd; d2 = d2 / nd;

    float pos[3], nr[3];
    for (int c = 0; c < 3; ++c) {
        pos[c] = (b0 * wv[i0 * 3 + c] + b1 * wv[i1 * 3 + c]) + b2 * wv[i2 * 3 + c];
    }
    nr[0] = (b0 * a0 + b1 * c0) + b2 * d0;
    nr[1] = (b0 * a1 + b1 * c1) + b2 * d1;
    nr[2] = (b0 * a2 + b1 * c2) + b2 * d2;
    float nl = sqrtf((nr[0] * nr[0] + nr[1] * nr[1]) + nr[2] * nr[2]) + 1e-8f;
    nr[0] = nr[0] / nl; nr[1] = nr[1] / nl; nr[2] = nr[2] / nl;

    // cam_i = -sum_j T_j * R[i][j]
    const float* tmb = tm + b * 16;
    float T0 = tmb[3], T1 = tmb[7], T2 = tmb[11];
    float cam[3];
    for (int i = 0; i < 3; ++i)
        cam[i] = -((T0 * tmb[i * 4 + 0] + T1 * tmb[i * 4 + 1]) + T2 * tmb[i * 4 + 2]);

    // L = normalize(light - pos), light = (0,0,3)
    float Lx = 0.0f - pos[0], Ly = 0.0f - pos[1], Lz = 3.0f - pos[2];
    float Ln = sqrtf((Lx * Lx + Ly * Ly) + Lz * Lz) + 1e-8f;
    Lx = Lx / Ln; Ly = Ly / Ln; Lz = Lz / Ln;
    // Vd = normalize(cam - pos)
    float Vx = cam[0] - pos[0], Vy = cam[1] - pos[1], Vz = cam[2] - pos[2];
    float Vn2 = sqrtf((Vx * Vx + Vy * Vy) + Vz * Vz) + 1e-8f;
    Vx = Vx / Vn2; Vy = Vy / Vn2; Vz = Vz / Vn2;

    float ndl = (nr[0] * Lx + nr[1] * Ly) + nr[2] * Lz;
    float t2 = 2.0f * ndl;
    float rx = (t2 * nr[0]) - Lx;
    float ry = (t2 * nr[1]) - Ly;
    float rz = (t2 * nr[2]) - Lz;
    float rv = (rx * Vx + ry * Vy) + rz * Vz;
    float sp = powf(fmaxf(rv, 0.0f), 64.0f);
    float spec = (0.2f * sp) * ((ndl > 0.0f) ? 1.0f : 0.0f);
    float col = (0.5f + 0.3f * fmaxf(ndl, 0.0f)) + spec;
    col = col * 255.0f;
    out[imgbase + 0 * PIX + p] = col;
    out[imgbase + 1 * PIX + p] = col;
    out[imgbase + 2 * PIX + p] = col;
    out[alphabase + p] = 1.0f;
}

extern "C" void kernel_launch(void* const* d_in, const int* in_sizes, int n_in,
                              void* d_out, int out_size, void* d_ws, size_t ws_size,
                              hipStream_t stream) {
    const float* verts = (const float*)d_in[0];
    const float* tm    = (const float*)d_in[1];
    const float* focal = (const float*)d_in[2];
    const float* pp    = (const float*)d_in[3];
    const int*   faces = (const int*)d_in[4];

    int B = in_sizes[1] / 16;
    int V = in_sizes[0] / (3 * B);
    int F = in_sizes[4] / 3;
    int FP = ((F + 255) / 256) * 256;  // pad; pad faces are degenerate -> inert

    float* out = (float*)d_out;

    // workspace layout (floats; zpk offset is 8-byte aligned: even float count)
    float* vp     = (float*)d_ws;            // B*V*3
    float* vn     = vp + (size_t)B * V * 3;  // B*V*3
    float* packed = vn + (size_t)B * V * 3;  // B*FP*9
    unsigned long long* zpk =
        (unsigned long long*)(packed + (size_t)B * FP * 9);  // B*PIX u64

    int nv = B * V;
    k_transform<<<dim3((nv + 255) / 256), dim3(256), 0, stream>>>(
        verts, tm, focal, pp, vp, vn, zpk, B, V);
    k_pack<<<dim3((B * FP + 255) / 256), dim3(256), 0, stream>>>(
        verts, faces, vp, packed, vn, B, F, FP, V);
    k_raster<<<dim3(FP / 4, B), dim3(256), 0, stream>>>(packed, zpk, FP);
    k_shade<<<dim3(PIX / 256, B), dim3(256), 0, stream>>>(
        verts, faces, tm, packed, vn, zpk, out, B, V, FP);
}